// Round 10
// baseline (266.472 us; speedup 1.0000x reference)
//
#include <hip/hip_runtime.h>
#include <math.h>

// RecurNN: B=256, L=256, E=100, T=255.
// x_t = W1L*left_t + W1R*right_t + b1; h_t = tanh(x_t); out = sigmoid(W2 h_254 + b2).
// These inputs: right_t always a leaf; left_t = node t-1 (leaf only at t=0).
//
// TWO batch rows per block (R9 + TLP): 128 blocks x 512 thr = 8 waves; each SIMD
// hosts 2 waves from INDEPENDENT chains -> stalls overlap. Per row:
//   waves 0,1 (consumers): lane l owns row e=50w+l, W1L[e][:] in 100 named
//     scalar VGPRs; h broadcast via v_readlane (no LDS streaming).
//   waves 2,3 (producers): c[t] = b1 + W1R*emb[right-leaf], emb rows fetched
//     coalesced per-lane, double-buffered; write 4-slot LDS c-ring.
// h history: 64-row LDS ring (covers n > t-64 race-free) + fire-and-forget
// global mirror in d_ws for deep generic references (volatile reads).
// Sync: one "s_waitcnt lgkmcnt(0); s_barrier" per step (no vmcnt drain).

#define Bc 256
#define Lc 256
#define Ec 100
#define Tc 255
#define W1cols 200
#define LEAD 2
#define RD 64           // LDS h-ring depth

#define RL(v, k) __int_as_float(__builtin_amdgcn_readlane(__float_as_int(v), (k)))

#define REP100(X) \
 X(0,0) X(1,1) X(2,2) X(3,3) X(4,0) X(5,1) X(6,2) X(7,3) \
 X(8,0) X(9,1) X(10,2) X(11,3) X(12,0) X(13,1) X(14,2) X(15,3) \
 X(16,0) X(17,1) X(18,2) X(19,3) X(20,0) X(21,1) X(22,2) X(23,3) \
 X(24,0) X(25,1) X(26,2) X(27,3) X(28,0) X(29,1) X(30,2) X(31,3) \
 X(32,0) X(33,1) X(34,2) X(35,3) X(36,0) X(37,1) X(38,2) X(39,3) \
 X(40,0) X(41,1) X(42,2) X(43,3) X(44,0) X(45,1) X(46,2) X(47,3) \
 X(48,0) X(49,1) X(50,2) X(51,3) X(52,0) X(53,1) X(54,2) X(55,3) \
 X(56,0) X(57,1) X(58,2) X(59,3) X(60,0) X(61,1) X(62,2) X(63,3) \
 X(64,0) X(65,1) X(66,2) X(67,3) X(68,0) X(69,1) X(70,2) X(71,3) \
 X(72,0) X(73,1) X(74,2) X(75,3) X(76,0) X(77,1) X(78,2) X(79,3) \
 X(80,0) X(81,1) X(82,2) X(83,3) X(84,0) X(85,1) X(86,2) X(87,3) \
 X(88,0) X(89,1) X(90,2) X(91,3) X(92,0) X(93,1) X(94,2) X(95,3) \
 X(96,0) X(97,1) X(98,2) X(99,3)

#define DECLW(k, c) float w##k;
// generic / producer: 100-vector in vA (lane k = k<64) + vB (lane k-64)
#define MACCP(k, c) acc##c = fmaf(RL((k) < 64 ? vA : vB, (k) < 64 ? (k) : (k) - 64), w##k, acc##c);
// consumer fast path, wave 0: k<50 in vh (lane k), k>=50 in vo (lane k-50)
#define MACC0(k, c) acc##c = fmaf(RL((k) < 50 ? vh : vo, (k) < 50 ? (k) : (k) - 50), w##k, acc##c);
// consumer fast path, wave 1: k<50 in vo (lane k), k>=50 in vh (lane k-50)
#define MACC1(k, c) acc##c = fmaf(RL((k) < 50 ? vo : vh, (k) < 50 ? (k) : (k) - 50), w##k, acc##c);

__global__ __launch_bounds__(512, 2)
void fused2(const int* __restrict__ token_ids,
            const int* __restrict__ comp_left,
            const int* __restrict__ comp_right,
            const float* __restrict__ emb,
            const float* __restrict__ W1,
            const float* __restrict__ b1,
            const float* __restrict__ W2,
            const float* __restrict__ b2,
            float* __restrict__ hist_ws,
            float* __restrict__ out)
{
    const int tid   = threadIdx.x;            // 0..511
    const int row   = tid >> 8;               // 0,1: which batch row of this block
    const int t256  = tid & 255;
    const int wv    = t256 >> 6;              // 0,1 consumers; 2,3 producers
    const int l     = tid & 63;
    const bool cons = (wv < 2);
    const int  lc   = (l < 50) ? l : 49;
    const int  b    = 2 * blockIdx.x + row;

    __shared__ float ring[2][RD][Ec];         // 51200 B h-ring
    __shared__ float cring[2][4][Ec];         // 3200 B c-ring
    __shared__ int2  ccS[2][Tc];              // 4080 B comp indices
    __shared__ int   tokRS[2][Tc], tokLS[2][Tc];  // 4080 B leaf tokens (-1 = internal)
    __shared__ float red[2][2];

    // ---- prologue staging (per row, 256 threads) ----
    for (int i = t256; i < Tc; i += 256) {
        const int cl = comp_left [b * Tc + i];
        const int cr = comp_right[b * Tc + i];
        ccS[row][i]   = make_int2(cl, cr);
        tokRS[row][i] = (cr < Lc) ? token_ids[b * Lc + cr] : -1;
        tokLS[row][i] = (cl < Lc) ? token_ids[b * Lc + cl] : -1;
    }

    // ---- role weights: consumer = W1L row, producer = W1R row ----
    const int erow = cons ? (50 * wv + lc) : (50 * (wv - 2) + lc);
    const float* wrow = W1 + (size_t)erow * W1cols + (cons ? 0 : Ec);
    REP100(DECLW)
#define LOADW(k, c) w##k = wrow[k];
    REP100(LOADW)
#undef LOADW
    const float b1e = b1[erow];
    const float w2e = W2[erow];
    const float b2v = b2[0];
    float* const mir = hist_ws + (size_t)b * Tc * Ec;   // global h mirror (this row)

    __syncthreads();

    // producer prefetch state (emb row k-distributed across lanes)
    float vA = 0.f, vB = 0.f;
    if (!cons) {
        const int t0 = __builtin_amdgcn_readfirstlane(tokRS[row][0]);
        if (t0 >= 0) {
            const float* g = emb + (size_t)t0 * Ec;
            vA = g[l];
            if (l < 36) vB = g[64 + l];
        }
    }
    float vh = 0.f;    // consumer: this lane's h (row erow), lanes 0-49 valid

    // ---- main loop: iter i => producer builds c[i], consumer does step i-LEAD ----
    #pragma unroll 1
    for (int i = 0; i < Tc + LEAD; ++i) {
        if (!cons) {
            // ================= PRODUCER =================
            if (i < Tc) {
                float nA = 0.f, nB = 0.f;
                if (i + 1 < Tc) {
                    const int tn = __builtin_amdgcn_readfirstlane(tokRS[row][i + 1]);
                    if (tn >= 0) {
                        const float* g = emb + (size_t)tn * Ec;
                        nA = g[l];
                        if (l < 36) nB = g[64 + l];
                    }
                }
                float acc0 = b1e, acc1 = 0.f, acc2 = 0.f, acc3 = 0.f;
                const int tcur = __builtin_amdgcn_readfirstlane(tokRS[row][i]);
                if (tcur >= 0) { REP100(MACCP) }     // right leaf (always, these inputs)
                if (l < 50) cring[row][i & 3][erow] = ((acc0 + acc1) + (acc2 + acc3));
                vA = nA; vB = nB;
            }
        } else {
            // ================= CONSUMER =================
            const int tc = i - LEAD;
            if (tc >= 0) {
                const int2 cc = ccS[row][tc];
                const int  li = __builtin_amdgcn_readfirstlane(cc.x);
                const int  ri = __builtin_amdgcn_readfirstlane(cc.y);
                float cv = (l < 50) ? cring[row][tc & 3][erow] : 0.f;
                float acc0 = 0.f, acc1 = 0.f, acc2 = 0.f, acc3 = 0.f;
                float vo = 0.f;

                if (tc >= 1 && li == Lc + tc - 1) {
                    // fast path: left = previous node; own half in vh, read other 50
                    const float* hrow = &ring[row][(tc - 1) & (RD - 1)][0];
                    if (l < 50) vo = hrow[(wv == 0) ? (50 + l) : l];
                    if (wv == 0) { REP100(MACC0) } else { REP100(MACC1) }
                } else if (li >= Lc) {
                    // generic internal node n (n >= tc -> zeros, per reference)
                    const int n = li - Lc;
                    if (n < tc) {
                        if (n > tc - RD) {         // ring window (race-free)
                            const float* hrow = &ring[row][n & (RD - 1)][0];
                            vA = hrow[l];
                            vB = (l < 36) ? hrow[64 + l] : 0.f;
                        } else {                   // deep: global mirror (>=RD steps old)
                            const volatile float* hrow = mir + (size_t)n * Ec;
                            vA = hrow[l];
                            vB = (l < 36) ? hrow[64 + l] : 0.f;
                        }
                        REP100(MACCP)
                    }
                } else {
                    // left leaf (t==0 for these inputs): emb row, per-lane coalesced
                    const int tl = __builtin_amdgcn_readfirstlane(tokLS[row][tc]);
                    const float* g = emb + (size_t)max(tl, 0) * Ec;
                    vA = g[l];
                    vB = (l < 36) ? g[64 + l] : 0.f;
                    REP100(MACCP)
                }

                if (ri >= Lc) {
                    // generic right-internal (never these inputs): global W1R, dyn readlane
                    const int n = ri - Lc;
                    if (n < tc) {
                        if (n > tc - RD) {
                            const float* hrow = &ring[row][n & (RD - 1)][0];
                            vA = hrow[l];
                            vB = (l < 36) ? hrow[64 + l] : 0.f;
                        } else {
                            const volatile float* hrow = mir + (size_t)n * Ec;
                            vA = hrow[l];
                            vB = (l < 36) ? hrow[64 + l] : 0.f;
                        }
                        const float* wr = W1 + (size_t)erow * W1cols + Ec;
                        for (int k = 0; k < Ec; ++k) {
                            float hv = __int_as_float(__builtin_amdgcn_readlane(
                                __float_as_int(k < 64 ? vA : vB), k < 64 ? k : k - 64));
                            acc0 = fmaf(hv, wr[k], acc0);
                        }
                    }
                }

                const float x = ((acc0 + acc1) + (acc2 + acc3)) + cv;
                const float u = __expf(2.f * x);
                vh = 1.f - 2.f / (u + 1.f);          // tanh, exact identity
                if (l < 50) {
                    ring[row][tc & (RD - 1)][erow] = vh;
                    mir[(size_t)tc * Ec + erow] = vh;   // fire-and-forget mirror
                }
            }
        }
        // one barrier per step; NO vmcnt drain (prefetch/mirror stay in flight)
        asm volatile("s_waitcnt lgkmcnt(0)\n\ts_barrier" ::: "memory");
    }

    // ---- out[b] = sigmoid(W2 . h_254 + b2) ----
    if (cons) {
        float p = (l < 50) ? w2e * vh : 0.f;
        #pragma unroll
        for (int off = 32; off > 0; off >>= 1) p += __shfl_down(p, off, 64);
        if (l == 0) red[row][wv] = p;
    }
    __syncthreads();
    if (t256 == 0) out[b] = 1.f / (1.f + __expf(-(red[row][0] + red[row][1] + b2v)));
}

extern "C" void kernel_launch(void* const* d_in, const int* in_sizes, int n_in,
                              void* d_out, int out_size, void* d_ws, size_t ws_size,
                              hipStream_t stream) {
    const int*   token_ids  = (const int*)  d_in[0];
    const int*   comp_left  = (const int*)  d_in[1];
    const int*   comp_right = (const int*)  d_in[2];
    const float* emb        = (const float*)d_in[3];
    const float* W1         = (const float*)d_in[4];
    const float* b1         = (const float*)d_in[5];
    const float* W2         = (const float*)d_in[6];
    const float* b2         = (const float*)d_in[7];
    float*       out        = (float*)d_out;
    float*       hist_ws    = (float*)d_ws;   // B*T*E*4 = 26,112,000 B <= ws_size

    fused2<<<Bc / 2, 512, 0, stream>>>(token_ids, comp_left, comp_right,
                                       emb, W1, b1, W2, b2, hist_ws, out);
}

// Round 11
// 190.099 us; speedup vs baseline: 1.4018x; 1.4018x over previous
//
#include <hip/hip_runtime.h>
#include <math.h>

// RecurNN: B=256, L=256, E=100, T=255.
// x_t = W1L*left_t + W1R*right_t + b1; h_t = tanh(x_t); out = sigmoid(W2 h_254 + b2).
// These inputs: right_t always a leaf; left_t = node t-1 (leaf only at t=0).
//
// R9 structure (183us) + hazard fixes:
//   one block per batch row, 256 thr = 4 waves (1/SIMD):
//   waves 0,1 (consumers): lane l owns row e=50w+l, W1L[e][:] in 100 named
//     scalar VGPRs; h broadcast via v_readlane.
//   waves 2,3 (producers): c[t] = b1 + W1R*emb[right-leaf], coalesced per-lane
//     emb loads double-buffered; 4-slot LDS c-ring.
//   Sync: one "s_waitcnt lgkmcnt(0); s_barrier" per step (no vmcnt drain).
// R11 changes (kill the ~1100 cyc/step of stalls):
//   1. readlanes batched x8 before their fmacs -> no VALU-write-SGPR hazard
//      stall per pair (was ~8 cyc x 100 = 800 cyc/step).
//   2. comp indices (cc) and producer token kept in registers, prefetched one
//      step ahead -> no LDS->readfirstlane->branch chain at step start.
//   3. fmac groups k-ascending: vh-half (k<50) first, so the vo LDS read
//      latency hides under ~12 groups of issue.

#define Bc 256
#define Lc 256
#define Ec 100
#define Tc 255
#define W1cols 200
#define LEAD 2

#define RL(v, k) __int_as_float(__builtin_amdgcn_readlane(__float_as_int(v), (k)))

// ---- weight registers w0..w99 (named scalars; proven resident R6/R9) ----
#define REP100(X) \
 X(0) X(1) X(2) X(3) X(4) X(5) X(6) X(7) X(8) X(9) X(10) X(11) X(12) X(13) X(14) X(15) \
 X(16) X(17) X(18) X(19) X(20) X(21) X(22) X(23) X(24) X(25) X(26) X(27) X(28) X(29) X(30) X(31) \
 X(32) X(33) X(34) X(35) X(36) X(37) X(38) X(39) X(40) X(41) X(42) X(43) X(44) X(45) X(46) X(47) \
 X(48) X(49) X(50) X(51) X(52) X(53) X(54) X(55) X(56) X(57) X(58) X(59) X(60) X(61) X(62) X(63) \
 X(64) X(65) X(66) X(67) X(68) X(69) X(70) X(71) X(72) X(73) X(74) X(75) X(76) X(77) X(78) X(79) \
 X(80) X(81) X(82) X(83) X(84) X(85) X(86) X(87) X(88) X(89) X(90) X(91) X(92) X(93) X(94) X(95) \
 X(96) X(97) X(98) X(99)

#define DECLW(k) float w##k;

// source selectors (k is a compile-time literal; ternaries fold)
#define SRC0(k) RL((k) < 50 ? vh : vo, (k) < 50 ? (k) : (k) - 50)   // consumer wave 0
#define SRC1(k) RL((k) < 50 ? vo : vh, (k) < 50 ? (k) : (k) - 50)   // consumer wave 1
#define SRCP(k) RL((k) < 64 ? vA : vB, (k) < 64 ? (k) : (k) - 64)   // producer / generic

// 8 readlanes batched, THEN 8 fmacs (4 acc chains) -> no SGPR-hazard stalls
#define G8(S,a,b,c,d,e,f,g,h2) { \
    const float r0_=S(a), r1_=S(b), r2_=S(c), r3_=S(d), \
                r4_=S(e), r5_=S(f), r6_=S(g), r7_=S(h2); \
    acc0 = fmaf(r0_, w##a, acc0); acc1 = fmaf(r1_, w##b, acc1); \
    acc2 = fmaf(r2_, w##c, acc2); acc3 = fmaf(r3_, w##d, acc3); \
    acc0 = fmaf(r4_, w##e, acc0); acc1 = fmaf(r5_, w##f, acc1); \
    acc2 = fmaf(r6_, w##g, acc2); acc3 = fmaf(r7_, w##h2, acc3); }
#define G4(S,a,b,c,d) { \
    const float r0_=S(a), r1_=S(b), r2_=S(c), r3_=S(d); \
    acc0 = fmaf(r0_, w##a, acc0); acc1 = fmaf(r1_, w##b, acc1); \
    acc2 = fmaf(r2_, w##c, acc2); acc3 = fmaf(r3_, w##d, acc3); }

#define GALL(S) \
    G8(S,0,1,2,3,4,5,6,7)         G8(S,8,9,10,11,12,13,14,15) \
    G8(S,16,17,18,19,20,21,22,23) G8(S,24,25,26,27,28,29,30,31) \
    G8(S,32,33,34,35,36,37,38,39) G8(S,40,41,42,43,44,45,46,47) \
    G8(S,48,49,50,51,52,53,54,55) G8(S,56,57,58,59,60,61,62,63) \
    G8(S,64,65,66,67,68,69,70,71) G8(S,72,73,74,75,76,77,78,79) \
    G8(S,80,81,82,83,84,85,86,87) G8(S,88,89,90,91,92,93,94,95) \
    G4(S,96,97,98,99)

__global__ __launch_bounds__(256, 1)
void fused(const int* __restrict__ token_ids,
           const int* __restrict__ comp_left,
           const int* __restrict__ comp_right,
           const float* __restrict__ emb,
           const float* __restrict__ W1,
           const float* __restrict__ b1,
           const float* __restrict__ W2,
           const float* __restrict__ b2,
           float* __restrict__ out)
{
    const int b    = blockIdx.x;
    const int tid  = threadIdx.x;
    const int wv   = tid >> 6;            // 0,1 consumers; 2,3 producers
    const int l    = tid & 63;
    const bool cons = (wv < 2);
    const int lc   = (l < 50) ? l : 49;   // clamped row-lane

    __shared__ __align__(16) float hist[Tc * Ec];   // 102000 B (zero = unwritten)
    __shared__ float cring[4][Ec];                  // c ring (4 slots)
    __shared__ int2  ccS[Tc];                       // comp indices
    __shared__ int   tokRS[Tc], tokLS[Tc];          // leaf tokens (-1 = internal)
    __shared__ float red[2];

    // ---- prologue staging (all waves) ----
    for (int i = tid; i < Tc; i += 256) {
        const int cl = comp_left [b * Tc + i];
        const int cr = comp_right[b * Tc + i];
        ccS[i]   = make_int2(cl, cr);
        tokRS[i] = (cr < Lc) ? token_ids[b * Lc + cr] : -1;
        tokLS[i] = (cl < Lc) ? token_ids[b * Lc + cl] : -1;
    }
    {   const float4 z4 = make_float4(0.f, 0.f, 0.f, 0.f);
        for (int i = tid; i < (Tc * Ec) / 4; i += 256) ((float4*)hist)[i] = z4;
    }

    // ---- role weights: consumer = W1L row, producer = W1R row ----
    const int erow = cons ? (50 * wv + lc) : (50 * (wv - 2) + lc);
    const float* wrow = W1 + (size_t)erow * W1cols + (cons ? 0 : Ec);
    REP100(DECLW)
#define LOADW(k) w##k = wrow[k];
    REP100(LOADW)
#undef LOADW
    const float b1e = b1[erow];
    const float w2e = W2[erow];
    const float b2v = b2[0];

    __syncthreads();    // staging + weights visible

    // register-rotated state (prefetched one step ahead; no LDS on step-start path)
    float vA = 0.f, vB = 0.f;          // producer emb row / generic h row
    int   tok_cur = -1;
    int2  cc = make_int2(0, 0);
    if (!cons) {
        tok_cur = __builtin_amdgcn_readfirstlane(tokRS[0]);
        if (tok_cur >= 0) {
            const float* g = emb + (size_t)tok_cur * Ec;
            vA = g[l];
            if (l < 36) vB = g[64 + l];
        }
    } else {
        cc = ccS[0];
    }
    float vh = 0.f;     // consumer: this lane's h (row erow), lanes 0-49 valid

    // ---- main loop: iter i => producer builds c[i], consumer does step i-LEAD ----
    #pragma unroll 1
    for (int i = 0; i < Tc + LEAD; ++i) {
        if (!cons) {
            // ================= PRODUCER =================
            if (i < Tc) {
                // prefetch next token + emb row (lands during this step / barrier)
                int tok_next = -1;
                float nA = 0.f, nB = 0.f;
                if (i + 1 < Tc) {
                    tok_next = __builtin_amdgcn_readfirstlane(tokRS[i + 1]);
                    if (tok_next >= 0) {
                        const float* g = emb + (size_t)tok_next * Ec;
                        nA = g[l];
                        if (l < 36) nB = g[64 + l];
                    }
                }
                float acc0 = b1e, acc1 = 0.f, acc2 = 0.f, acc3 = 0.f;
                if (tok_cur >= 0) { GALL(SRCP) }     // right leaf (always, these inputs)
                if (l < 50) cring[i & 3][erow] = ((acc0 + acc1) + (acc2 + acc3));
                vA = nA; vB = nB; tok_cur = tok_next;
            }
        } else {
            // ================= CONSUMER =================
            const int tc = i - LEAD;
            if (tc >= 0) {
                const int li = __builtin_amdgcn_readfirstlane(cc.x);
                const int ri = __builtin_amdgcn_readfirstlane(cc.y);
                float cv = (l < 50) ? cring[tc & 3][erow] : 0.f;
                float acc0 = 0.f, acc1 = 0.f, acc2 = 0.f, acc3 = 0.f;
                float vo = 0.f;

                if (tc >= 1 && li == Lc + tc - 1) {
                    // fast path: left = previous node; own half in vh, read other 50.
                    // vo read issues FIRST; groups k<50 (vh-only) hide its latency.
                    const float* hrow = &hist[(size_t)(tc - 1) * Ec];
                    if (l < 50) vo = hrow[(wv == 0) ? (50 + l) : l];
                    if (wv == 0) { GALL(SRC0) } else { GALL(SRC1) }
                } else if (li >= Lc) {
                    // generic internal node n (n >= tc -> zeros, per reference)
                    const int n = min(li - Lc, Tc - 1);
                    const float* hrow = &hist[(size_t)n * Ec];
                    vA = hrow[l];
                    vB = (l < 36) ? hrow[64 + l] : 0.f;
                    GALL(SRCP)
                } else {
                    // left leaf (t==0 for these inputs): emb row, per-lane coalesced
                    const int tl = __builtin_amdgcn_readfirstlane(tokLS[tc]);
                    const float* g = emb + (size_t)max(tl, 0) * Ec;
                    vA = g[l];
                    vB = (l < 36) ? g[64 + l] : 0.f;
                    GALL(SRCP)
                }

                if (ri >= Lc) {
                    // generic right-internal (never these inputs): global W1R, dyn readlane
                    const int n = min(ri - Lc, Tc - 1);
                    const float* hrow = &hist[(size_t)n * Ec];
                    vA = hrow[l];
                    vB = (l < 36) ? hrow[64 + l] : 0.f;
                    const float* wr = W1 + (size_t)erow * W1cols + Ec;
                    for (int k = 0; k < Ec; ++k) {
                        float hv = __int_as_float(__builtin_amdgcn_readlane(
                            __float_as_int(k < 64 ? vA : vB), k < 64 ? k : k - 64));
                        acc0 = fmaf(hv, wr[k], acc0);
                    }
                }

                const float x = ((acc0 + acc1) + (acc2 + acc3)) + cv;
                const float u = __expf(2.f * x);
                vh = 1.f - 2.f / (u + 1.f);          // tanh, exact identity
                if (l < 50) hist[(size_t)tc * Ec + erow] = vh;
                if (tc + 1 < Tc) cc = ccS[tc + 1];   // rotate: next step's indices
            }
        }
        // one barrier per step: order DS writes -> next-step DS reads.
        // NO vmcnt drain (producer prefetch stays in flight across the barrier).
        asm volatile("s_waitcnt lgkmcnt(0)\n\ts_barrier" ::: "memory");
    }

    // ---- out[b] = sigmoid(W2 . h_254 + b2) ----
    if (cons) {
        float p = (l < 50) ? w2e * vh : 0.f;
        #pragma unroll
        for (int off = 32; off > 0; off >>= 1) p += __shfl_down(p, off, 64);
        if (l == 0) red[wv] = p;
    }
    __syncthreads();
    if (tid == 0) out[b] = 1.f / (1.f + __expf(-(red[0] + red[1] + b2v)));
}

extern "C" void kernel_launch(void* const* d_in, const int* in_sizes, int n_in,
                              void* d_out, int out_size, void* d_ws, size_t ws_size,
                              hipStream_t stream) {
    const int*   token_ids  = (const int*)  d_in[0];
    const int*   comp_left  = (const int*)  d_in[1];
    const int*   comp_right = (const int*)  d_in[2];
    const float* emb        = (const float*)d_in[3];
    const float* W1         = (const float*)d_in[4];
    const float* b1         = (const float*)d_in[5];
    const float* W2         = (const float*)d_in[6];
    const float* b2         = (const float*)d_in[7];
    float*       out        = (float*)d_out;

    fused<<<Bc, 256, 0, stream>>>(token_ids, comp_left, comp_right,
                                  emb, W1, b1, W2, b2, out);
}

// Round 12
// 184.925 us; speedup vs baseline: 1.4410x; 1.0280x over previous
//
#include <hip/hip_runtime.h>
#include <math.h>

// RecurNN: B=256, L=256, E=100, T=255.
// x_t = W1L*left_t + W1R*right_t + b1; h_t = tanh(x_t); out = sigmoid(W2 h_254 + b2).
// These inputs: right_t always a leaf; left_t = node t-1 (leaf only at t=0).
//
// R11 structure (190us) with ONE change: producer emb prefetch is 2 STEPS deep
// (3 rotating register sets). R11's 1-step slack (< L3 latency ~500-900 cyc)
// made the producer wait on vmcnt nearly every iteration; the per-step barrier
// then propagated that stall to the whole block (R6-phaseB had the same bug,
// same ~1760 cyc/step). With 2-step slack the load window is ~2000+ cyc.
//
//   one block per batch row, 256 thr = 4 waves (1/SIMD):
//   waves 0,1 (consumers): lane l owns row e=50w+l, W1L[e][:] in 100 named
//     scalar VGPRs; h broadcast via v_readlane; own-half groups first so the
//     cross-half LDS read (vo) latency hides under issue.
//   waves 2,3 (producers): c[t] = b1 + W1R*emb[right-leaf]; 4-slot LDS c-ring.
//   Sync: one "s_waitcnt lgkmcnt(0); s_barrier" per step (no vmcnt drain).

#define Bc 256
#define Lc 256
#define Ec 100
#define Tc 255
#define W1cols 200
#define LEAD 2

#define RL(v, k) __int_as_float(__builtin_amdgcn_readlane(__float_as_int(v), (k)))

// ---- weight registers w0..w99 (named scalars; proven resident R6/R9/R11) ----
#define REP100(X) \
 X(0) X(1) X(2) X(3) X(4) X(5) X(6) X(7) X(8) X(9) X(10) X(11) X(12) X(13) X(14) X(15) \
 X(16) X(17) X(18) X(19) X(20) X(21) X(22) X(23) X(24) X(25) X(26) X(27) X(28) X(29) X(30) X(31) \
 X(32) X(33) X(34) X(35) X(36) X(37) X(38) X(39) X(40) X(41) X(42) X(43) X(44) X(45) X(46) X(47) \
 X(48) X(49) X(50) X(51) X(52) X(53) X(54) X(55) X(56) X(57) X(58) X(59) X(60) X(61) X(62) X(63) \
 X(64) X(65) X(66) X(67) X(68) X(69) X(70) X(71) X(72) X(73) X(74) X(75) X(76) X(77) X(78) X(79) \
 X(80) X(81) X(82) X(83) X(84) X(85) X(86) X(87) X(88) X(89) X(90) X(91) X(92) X(93) X(94) X(95) \
 X(96) X(97) X(98) X(99)

#define DECLW(k) float w##k;

// source selectors (k is a compile-time literal; ternaries fold)
#define SRC0(k) RL((k) < 50 ? vh : vo, (k) < 50 ? (k) : (k) - 50)   // consumer wave 0
#define SRC1(k) RL((k) < 50 ? vo : vh, (k) < 50 ? (k) : (k) - 50)   // consumer wave 1
#define SRCP(k) RL((k) < 64 ? vA : vB, (k) < 64 ? (k) : (k) - 64)   // producer / generic

// 8 readlanes batched, THEN 8 fmacs (4 acc chains)
#define G8(S,a,b,c,d,e,f,g,h2) { \
    const float r0_=S(a), r1_=S(b), r2_=S(c), r3_=S(d), \
                r4_=S(e), r5_=S(f), r6_=S(g), r7_=S(h2); \
    acc0 = fmaf(r0_, w##a, acc0); acc1 = fmaf(r1_, w##b, acc1); \
    acc2 = fmaf(r2_, w##c, acc2); acc3 = fmaf(r3_, w##d, acc3); \
    acc0 = fmaf(r4_, w##e, acc0); acc1 = fmaf(r5_, w##f, acc1); \
    acc2 = fmaf(r6_, w##g, acc2); acc3 = fmaf(r7_, w##h2, acc3); }
#define G4(S,a,b,c,d) { \
    const float r0_=S(a), r1_=S(b), r2_=S(c), r3_=S(d); \
    acc0 = fmaf(r0_, w##a, acc0); acc1 = fmaf(r1_, w##b, acc1); \
    acc2 = fmaf(r2_, w##c, acc2); acc3 = fmaf(r3_, w##d, acc3); }

#define GALL(S) \
    G8(S,0,1,2,3,4,5,6,7)         G8(S,8,9,10,11,12,13,14,15) \
    G8(S,16,17,18,19,20,21,22,23) G8(S,24,25,26,27,28,29,30,31) \
    G8(S,32,33,34,35,36,37,38,39) G8(S,40,41,42,43,44,45,46,47) \
    G8(S,48,49,50,51,52,53,54,55) G8(S,56,57,58,59,60,61,62,63) \
    G8(S,64,65,66,67,68,69,70,71) G8(S,72,73,74,75,76,77,78,79) \
    G8(S,80,81,82,83,84,85,86,87) G8(S,88,89,90,91,92,93,94,95) \
    G4(S,96,97,98,99)

__global__ __launch_bounds__(256, 1)
void fused(const int* __restrict__ token_ids,
           const int* __restrict__ comp_left,
           const int* __restrict__ comp_right,
           const float* __restrict__ emb,
           const float* __restrict__ W1,
           const float* __restrict__ b1,
           const float* __restrict__ W2,
           const float* __restrict__ b2,
           float* __restrict__ out)
{
    const int b    = blockIdx.x;
    const int tid  = threadIdx.x;
    const int wv   = tid >> 6;            // 0,1 consumers; 2,3 producers
    const int l    = tid & 63;
    const bool cons = (wv < 2);
    const int lc   = (l < 50) ? l : 49;   // clamped row-lane

    __shared__ __align__(16) float hist[Tc * Ec];   // 102000 B (zero = unwritten)
    __shared__ float cring[4][Ec];                  // c ring (4 slots)
    __shared__ int2  ccS[Tc];                       // comp indices
    __shared__ int   tokRS[Tc], tokLS[Tc];          // leaf tokens (-1 = internal)
    __shared__ float red[2];

    // ---- prologue staging (all waves) ----
    for (int i = tid; i < Tc; i += 256) {
        const int cl = comp_left [b * Tc + i];
        const int cr = comp_right[b * Tc + i];
        ccS[i]   = make_int2(cl, cr);
        tokRS[i] = (cr < Lc) ? token_ids[b * Lc + cr] : -1;
        tokLS[i] = (cl < Lc) ? token_ids[b * Lc + cl] : -1;
    }
    {   const float4 z4 = make_float4(0.f, 0.f, 0.f, 0.f);
        for (int i = tid; i < (Tc * Ec) / 4; i += 256) ((float4*)hist)[i] = z4;
    }

    // ---- role weights: consumer = W1L row, producer = W1R row ----
    const int erow = cons ? (50 * wv + lc) : (50 * (wv - 2) + lc);
    const float* wrow = W1 + (size_t)erow * W1cols + (cons ? 0 : Ec);
    REP100(DECLW)
#define LOADW(k) w##k = wrow[k];
    REP100(LOADW)
#undef LOADW
    const float b1e = b1[erow];
    const float w2e = W2[erow];
    const float b2v = b2[0];

    __syncthreads();    // staging + weights visible

    // ---- producer: 2-deep emb prefetch pipeline (3 rotating reg sets) ----
    float vA = 0.f, vB = 0.f;      // row for step i   (ready at use)
    float nA = 0.f, nB = 0.f;      // row for step i+1 (in flight)
    int   tok0 = -1, tok1 = -1;
    int2  cc = make_int2(0, 0);
    if (!cons) {
        tok0 = __builtin_amdgcn_readfirstlane(tokRS[0]);
        if (tok0 >= 0) {
            const float* g = emb + (size_t)tok0 * Ec;
            vA = g[l];
            if (l < 36) vB = g[64 + l];
        }
        if (1 < Tc) {
            tok1 = __builtin_amdgcn_readfirstlane(tokRS[1]);
            if (tok1 >= 0) {
                const float* g = emb + (size_t)tok1 * Ec;
                nA = g[l];
                if (l < 36) nB = g[64 + l];
            }
        }
    } else {
        cc = ccS[0];
    }
    float vh = 0.f;     // consumer: this lane's h (row erow), lanes 0-49 valid

    // ---- main loop: iter i => producer builds c[i], consumer does step i-LEAD ----
    #pragma unroll 1
    for (int i = 0; i < Tc + LEAD; ++i) {
        if (!cons) {
            // ================= PRODUCER =================
            if (i < Tc) {
                // issue prefetch for step i+2 (2 full steps of slack)
                int   tok2 = -1;
                float pA = 0.f, pB = 0.f;
                if (i + 2 < Tc) {
                    tok2 = __builtin_amdgcn_readfirstlane(tokRS[i + 2]);
                    if (tok2 >= 0) {
                        const float* g = emb + (size_t)tok2 * Ec;
                        pA = g[l];
                        if (l < 36) pB = g[64 + l];
                    }
                }
                // compute c[i] from the (ready) current row
                float acc0 = b1e, acc1 = 0.f, acc2 = 0.f, acc3 = 0.f;
                if (tok0 >= 0) { GALL(SRCP) }       // right leaf (always, these inputs)
                if (l < 50) cring[i & 3][erow] = ((acc0 + acc1) + (acc2 + acc3));
                // rotate pipeline
                vA = nA; vB = nB; tok0 = tok1;
                nA = pA; nB = pB; tok1 = tok2;
            }
        } else {
            // ================= CONSUMER =================
            const int tc = i - LEAD;
            if (tc >= 0) {
                const int li = __builtin_amdgcn_readfirstlane(cc.x);
                const int ri = __builtin_amdgcn_readfirstlane(cc.y);
                float cv = (l < 50) ? cring[tc & 3][erow] : 0.f;
                float acc0 = 0.f, acc1 = 0.f, acc2 = 0.f, acc3 = 0.f;
                float vo = 0.f;

                if (tc >= 1 && li == Lc + tc - 1) {
                    // fast path: left = previous node; own half in vh, other 50 via LDS.
                    // vo read issues first; own-half groups hide its latency.
                    const float* hrow = &hist[(size_t)(tc - 1) * Ec];
                    if (l < 50) vo = hrow[(wv == 0) ? (50 + l) : l];
                    if (wv == 0) { GALL(SRC0) } else { GALL(SRC1) }
                } else if (li >= Lc) {
                    // generic internal node n (n >= tc -> zeros, per reference)
                    const int n = min(li - Lc, Tc - 1);
                    const float* hrow = &hist[(size_t)n * Ec];
                    float gA = hrow[l];
                    float gB = (l < 36) ? hrow[64 + l] : 0.f;
                    { const float vA = gA, vB = gB; GALL(SRCP) }
                } else {
                    // left leaf (t==0 for these inputs): emb row, per-lane coalesced
                    const int tl = __builtin_amdgcn_readfirstlane(tokLS[tc]);
                    const float* g = emb + (size_t)max(tl, 0) * Ec;
                    float gA = g[l];
                    float gB = (l < 36) ? g[64 + l] : 0.f;
                    { const float vA = gA, vB = gB; GALL(SRCP) }
                }

                if (ri >= Lc) {
                    // generic right-internal (never these inputs): global W1R, dyn readlane
                    const int n = min(ri - Lc, Tc - 1);
                    const float* hrow = &hist[(size_t)n * Ec];
                    float gA = hrow[l];
                    float gB = (l < 36) ? hrow[64 + l] : 0.f;
                    const float* wr = W1 + (size_t)erow * W1cols + Ec;
                    for (int k = 0; k < Ec; ++k) {
                        float hv = __int_as_float(__builtin_amdgcn_readlane(
                            __float_as_int(k < 64 ? gA : gB), k < 64 ? k : k - 64));
                        acc0 = fmaf(hv, wr[k], acc0);
                    }
                }

                const float x = ((acc0 + acc1) + (acc2 + acc3)) + cv;
                const float u = __expf(2.f * x);
                vh = 1.f - 2.f / (u + 1.f);          // tanh, exact identity
                if (l < 50) hist[(size_t)tc * Ec + erow] = vh;
                if (tc + 1 < Tc) cc = ccS[tc + 1];   // rotate: next step's indices
            }
        }
        // one barrier per step: order DS writes -> next-step DS reads.
        // NO vmcnt drain (producer prefetch stays in flight across the barrier).
        asm volatile("s_waitcnt lgkmcnt(0)\n\ts_barrier" ::: "memory");
    }

    // ---- out[b] = sigmoid(W2 . h_254 + b2) ----
    if (cons) {
        float p = (l < 50) ? w2e * vh : 0.f;
        #pragma unroll
        for (int off = 32; off > 0; off >>= 1) p += __shfl_down(p, off, 64);
        if (l == 0) red[wv] = p;
    }
    __syncthreads();
    if (tid == 0) out[b] = 1.f / (1.f + __expf(-(red[0] + red[1] + b2v)));
}

extern "C" void kernel_launch(void* const* d_in, const int* in_sizes, int n_in,
                              void* d_out, int out_size, void* d_ws, size_t ws_size,
                              hipStream_t stream) {
    const int*   token_ids  = (const int*)  d_in[0];
    const int*   comp_left  = (const int*)  d_in[1];
    const int*   comp_right = (const int*)  d_in[2];
    const float* emb        = (const float*)d_in[3];
    const float* W1         = (const float*)d_in[4];
    const float* b1         = (const float*)d_in[5];
    const float* W2         = (const float*)d_in[6];
    const float* b2         = (const float*)d_in[7];
    float*       out        = (float*)d_out;

    fused<<<Bc, 256, 0, stream>>>(token_ids, comp_left, comp_right,
                                  emb, W1, b1, W2, b2, out);
}

// Round 13
// 156.487 us; speedup vs baseline: 1.7028x; 1.1817x over previous
//
#include <hip/hip_runtime.h>
#include <math.h>

// RecurNN: B=256, L=256, E=100, T=255.
// x_t = W1L*left_t + W1R*right_t + b1; h_t = tanh(x_t); out = sigmoid(W2 h_254 + b2).
// These inputs: right_t always a leaf; left_t = node t-1 (leaf only at t=0).
//
// Fused producer/consumer (R9 lineage), one block per batch row, 4 waves:
//   waves 0,1 consumers (rows 0-49 / 50-99, W1L row in 100 named scalar VGPRs,
//   h broadcast via v_readlane); waves 2,3 producers (W1R rows, c into 4-slot
//   LDS ring). One "lgkmcnt(0); s_barrier" per step, vmcnt NOT drained.
//
// R13 changes:
//  1. TRUE 2-step producer prefetch: unroll-2 ping-pong register sets (E/O),
//     no rotation movs (R12's movs forced the vmcnt wait inside the same
//     iteration -> only ~400cyc slack; now ~2 steps ≈ 1300+ cyc > L3 latency).
//  2. Rare paths (left-leaf, deep internal, right-internal) call a __noinline__
//     slow_dot with global weights -> hot loop ~10KB (R7 I-cache lesson).
//  3. ccS[tc+1] prefetch moved early so its DS latency hides under the matvec.

#define Bc 256
#define Lc 256
#define Ec 100
#define Tc 255
#define W1cols 200
#define LEAD 2

#define RL(v, k) __int_as_float(__builtin_amdgcn_readlane(__float_as_int(v), (k)))

#define REP100(X) \
 X(0) X(1) X(2) X(3) X(4) X(5) X(6) X(7) X(8) X(9) X(10) X(11) X(12) X(13) X(14) X(15) \
 X(16) X(17) X(18) X(19) X(20) X(21) X(22) X(23) X(24) X(25) X(26) X(27) X(28) X(29) X(30) X(31) \
 X(32) X(33) X(34) X(35) X(36) X(37) X(38) X(39) X(40) X(41) X(42) X(43) X(44) X(45) X(46) X(47) \
 X(48) X(49) X(50) X(51) X(52) X(53) X(54) X(55) X(56) X(57) X(58) X(59) X(60) X(61) X(62) X(63) \
 X(64) X(65) X(66) X(67) X(68) X(69) X(70) X(71) X(72) X(73) X(74) X(75) X(76) X(77) X(78) X(79) \
 X(80) X(81) X(82) X(83) X(84) X(85) X(86) X(87) X(88) X(89) X(90) X(91) X(92) X(93) X(94) X(95) \
 X(96) X(97) X(98) X(99)

#define DECLW(k) float w##k;

// source selectors (k is a compile-time literal; ternaries fold)
#define SRC0(k) RL((k) < 50 ? vh : vo, (k) < 50 ? (k) : (k) - 50)   // consumer wave 0
#define SRC1(k) RL((k) < 50 ? vo : vh, (k) < 50 ? (k) : (k) - 50)   // consumer wave 1
#define SRCP(k) RL((k) < 64 ? vA : vB, (k) < 64 ? (k) : (k) - 64)   // producer

#define G8(S,a,b,c,d,e,f,g,h2) { \
    const float r0_=S(a), r1_=S(b), r2_=S(c), r3_=S(d), \
                r4_=S(e), r5_=S(f), r6_=S(g), r7_=S(h2); \
    acc0 = fmaf(r0_, w##a, acc0); acc1 = fmaf(r1_, w##b, acc1); \
    acc2 = fmaf(r2_, w##c, acc2); acc3 = fmaf(r3_, w##d, acc3); \
    acc0 = fmaf(r4_, w##e, acc0); acc1 = fmaf(r5_, w##f, acc1); \
    acc2 = fmaf(r6_, w##g, acc2); acc3 = fmaf(r7_, w##h2, acc3); }
#define G4(S,a,b,c,d) { \
    const float r0_=S(a), r1_=S(b), r2_=S(c), r3_=S(d); \
    acc0 = fmaf(r0_, w##a, acc0); acc1 = fmaf(r1_, w##b, acc1); \
    acc2 = fmaf(r2_, w##c, acc2); acc3 = fmaf(r3_, w##d, acc3); }

#define GALL(S) \
    G8(S,0,1,2,3,4,5,6,7)         G8(S,8,9,10,11,12,13,14,15) \
    G8(S,16,17,18,19,20,21,22,23) G8(S,24,25,26,27,28,29,30,31) \
    G8(S,32,33,34,35,36,37,38,39) G8(S,40,41,42,43,44,45,46,47) \
    G8(S,48,49,50,51,52,53,54,55) G8(S,56,57,58,59,60,61,62,63) \
    G8(S,64,65,66,67,68,69,70,71) G8(S,72,73,74,75,76,77,78,79) \
    G8(S,80,81,82,83,84,85,86,87) G8(S,88,89,90,91,92,93,94,95) \
    G4(S,96,97,98,99)

// generic fallback dot (weights re-read from global; never hot for these inputs)
__device__ __noinline__ float slow_dot(const float* rp, const float* wr) {
    float a0 = 0.f, a1 = 0.f, a2 = 0.f, a3 = 0.f;
    for (int qq = 0; qq < 25; ++qq) {
        float4 h4 = *(const float4*)(rp + 4 * qq);
        float4 w4 = *(const float4*)(wr + 4 * qq);
        a0 = fmaf(w4.x, h4.x, a0); a1 = fmaf(w4.y, h4.y, a1);
        a2 = fmaf(w4.z, h4.z, a2); a3 = fmaf(w4.w, h4.w, a3);
    }
    return (a0 + a1) + (a2 + a3);
}

__global__ __launch_bounds__(256, 1)
void fused(const int* __restrict__ token_ids,
           const int* __restrict__ comp_left,
           const int* __restrict__ comp_right,
           const float* __restrict__ emb,
           const float* __restrict__ W1,
           const float* __restrict__ b1,
           const float* __restrict__ W2,
           const float* __restrict__ b2,
           float* __restrict__ out)
{
    const int b    = blockIdx.x;
    const int tid  = threadIdx.x;
    const int wv   = tid >> 6;            // 0,1 consumers; 2,3 producers
    const int l    = tid & 63;
    const bool cons = (wv < 2);
    const int lc   = (l < 50) ? l : 49;   // clamped row-lane

    __shared__ __align__(16) float hist[Tc * Ec];   // 102000 B (zero = unwritten)
    __shared__ float cring[4][Ec];                  // c ring (4 slots)
    __shared__ int2  ccS[Tc];                       // comp indices
    __shared__ int   tokRS[Tc], tokLS[Tc];          // leaf tokens (-1 = internal)
    __shared__ float red[2];

    // ---- prologue staging (all waves) ----
    for (int i = tid; i < Tc; i += 256) {
        const int cl = comp_left [b * Tc + i];
        const int cr = comp_right[b * Tc + i];
        ccS[i]   = make_int2(cl, cr);
        tokRS[i] = (cr < Lc) ? token_ids[b * Lc + cr] : -1;
        tokLS[i] = (cl < Lc) ? token_ids[b * Lc + cl] : -1;
    }
    {   const float4 z4 = make_float4(0.f, 0.f, 0.f, 0.f);
        for (int i = tid; i < (Tc * Ec) / 4; i += 256) ((float4*)hist)[i] = z4;
    }

    // ---- role weights: consumer = W1L row, producer = W1R row ----
    const int erow = cons ? (50 * wv + lc) : (50 * (wv - 2) + lc);
    const float* wrow = W1 + (size_t)erow * W1cols + (cons ? 0 : Ec);
    REP100(DECLW)
#define LOADW(k) w##k = wrow[k];
    REP100(LOADW)
#undef LOADW
    const float b1e = b1[erow];
    const float w2e = W2[erow];
    const float b2v = b2[0];

    __syncthreads();    // staging + weights visible

    // ---- state ----
    float eA0 = 0.f, eB0 = 0.f;   // producer emb row, EVEN steps
    float eA1 = 0.f, eB1 = 0.f;   // producer emb row, ODD steps
    int   tkE = -1, tkO = -1;
    int2  cc = make_int2(0, 0);
    float vh = 0.f;               // consumer: this lane's h, lanes 0-49 valid

    if (!cons) {
        tkE = __builtin_amdgcn_readfirstlane(tokRS[0]);
        if (tkE >= 0) {
            const float* g = emb + (size_t)tkE * Ec;
            eA0 = g[l];
            if (l < 36) eB0 = g[64 + l];
        }
        tkO = __builtin_amdgcn_readfirstlane(tokRS[1]);
        if (tkO >= 0) {
            const float* g = emb + (size_t)tkO * Ec;
            eA1 = g[l];
            if (l < 36) eB1 = g[64 + l];
        }
    } else {
        cc = ccS[0];
    }

// producer substep j: consume set (SA,SB,TK); reload it for step j+2
#define PROD_STEP(j, SA, SB, TK)                                              \
    if (!cons && (j) < Tc) {                                                  \
        int t2 = -1;                                                          \
        if ((j) + 2 < Tc) t2 = __builtin_amdgcn_readfirstlane(tokRS[(j) + 2]);\
        float acc0 = b1e, acc1 = 0.f, acc2 = 0.f, acc3 = 0.f;                 \
        if (TK >= 0) { const float vA = SA, vB = SB; GALL(SRCP) }             \
        if (t2 >= 0) {                                                        \
            const float* g = emb + (size_t)t2 * Ec;                           \
            SA = g[l];                                                        \
            SB = (l < 36) ? g[64 + l] : 0.f;                                  \
        } else { SA = 0.f; SB = 0.f; }                                        \
        if (l < 50) cring[(j) & 3][erow] = (acc0 + acc1) + (acc2 + acc3);     \
        TK = t2;                                                              \
    }

// consumer substep j: recurrence step tc = j-LEAD
#define CONS_STEP(j)                                                          \
    if (cons) {                                                               \
        const int tc = (j) - LEAD;                                            \
        if (tc >= 0 && tc < Tc) {                                             \
            const int li = __builtin_amdgcn_readfirstlane(cc.x);              \
            const int ri = __builtin_amdgcn_readfirstlane(cc.y);              \
            const int2 ccn = (tc + 1 < Tc) ? ccS[tc + 1] : make_int2(0, 0);   \
            float cv = (l < 50) ? cring[tc & 3][erow] : 0.f;                  \
            float acc0 = 0.f, acc1 = 0.f, acc2 = 0.f, acc3 = 0.f;             \
            if (tc >= 1 && li == Lc + tc - 1) {                               \
                const float* hrow = &hist[(size_t)(tc - 1) * Ec];             \
                float vo = 0.f;                                               \
                if (l < 50) vo = hrow[(wv == 0) ? (50 + l) : l];              \
                if (wv == 0) { GALL(SRC0) } else { GALL(SRC1) }               \
            } else if (li >= Lc) {                                            \
                acc0 += slow_dot(&hist[(size_t)min(li - Lc, Tc - 1) * Ec],    \
                                 W1 + (size_t)erow * W1cols);                 \
            } else {                                                          \
                const int tl = __builtin_amdgcn_readfirstlane(tokLS[tc]);     \
                acc0 += slow_dot(emb + (size_t)max(tl, 0) * Ec,               \
                                 W1 + (size_t)erow * W1cols);                 \
            }                                                                 \
            if (ri >= Lc)                                                     \
                acc0 += slow_dot(&hist[(size_t)min(ri - Lc, Tc - 1) * Ec],    \
                                 W1 + (size_t)erow * W1cols + Ec);            \
            const float x = ((acc0 + acc1) + (acc2 + acc3)) + cv;             \
            const float u = __expf(2.f * x);                                  \
            vh = 1.f - 2.f / (u + 1.f);                                       \
            if (l < 50) hist[(size_t)tc * Ec + erow] = vh;                    \
            cc = ccn;                                                         \
        }                                                                     \
    }

#define BARRIER asm volatile("s_waitcnt lgkmcnt(0)\n\ts_barrier" ::: "memory");

    // ---- main loop: 258 substeps (>= Tc+LEAD = 257), unroll-2 ping-pong ----
    #pragma unroll 1
    for (int i = 0; i < 258; i += 2) {
        PROD_STEP(i,     eA0, eB0, tkE)
        CONS_STEP(i)
        BARRIER
        PROD_STEP(i + 1, eA1, eB1, tkO)
        CONS_STEP(i + 1)
        BARRIER
    }

#undef PROD_STEP
#undef CONS_STEP
#undef BARRIER

    // ---- out[b] = sigmoid(W2 . h_254 + b2) ----
    if (cons) {
        float p = (l < 50) ? w2e * vh : 0.f;
        #pragma unroll
        for (int off = 32; off > 0; off >>= 1) p += __shfl_down(p, off, 64);
        if (l == 0) red[wv] = p;
    }
    __syncthreads();
    if (tid == 0) out[b] = 1.f / (1.f + __expf(-(red[0] + red[1] + b2v)));
}

extern "C" void kernel_launch(void* const* d_in, const int* in_sizes, int n_in,
                              void* d_out, int out_size, void* d_ws, size_t ws_size,
                              hipStream_t stream) {
    const int*   token_ids  = (const int*)  d_in[0];
    const int*   comp_left  = (const int*)  d_in[1];
    const int*   comp_right = (const int*)  d_in[2];
    const float* emb        = (const float*)d_in[3];
    const float* W1         = (const float*)d_in[4];
    const float* b1         = (const float*)d_in[5];
    const float* W2         = (const float*)d_in[6];
    const float* b2         = (const float*)d_in[7];
    float*       out        = (float*)d_out;

    fused<<<Bc, 256, 0, stream>>>(token_ids, comp_left, comp_right,
                                  emb, W1, b1, W2, b2, out);
}